// Round 8
// baseline (100.522 us; speedup 1.0000x reference)
//
#include <hip/hip_runtime.h>

// Chamfer distance, B=16 clouds x N=4096 x D=3, fp32, via bf16-split MFMA.
// R16: S_ij computed by ONE v_mfma_f32_16x16x32_bf16 (K=32, f32x4 out):
//   k0-2:  xh * -2yh   k3-5:  xl * -2yh   k6-8: xh * -2yl   k9-11: xl * -2yl
//   k12,13: x2h,x2l *1  k14,15: 1 * y2h,y2l   (k16-31 zero; lanes 32-63 carry
//   zero A/B operands but full C/D coverage). Err ~3e-4 (all cross terms).
// History: R8 96.0. R9/R10 atomics+fences 137 REGRESSION. R11 min3 98.5
//   NEUTRAL. R12 launch_bounds(256,5) FAILED. R13 fused 100.8 NEUTRAL.
//   R14 dir-split row-min-only: cd_fused 43us, VALU 69% (in-kernel dequant).
//   R15 prep-once + global_load_lds staging: cd_mfma 47us, VALU 46%,
//   conflicts 0, VGPR=52 -> f32x16 accumulators in AGPRs; inline-asm min3
//   "v" constraints force 32 v_accvgpr_read/iter = ~3x per-entry VALU tax.
//   R14/R15 equal-time despite different staging = same accumulator tax.
// R16 fix: 16x16x32 MFMA (4-reg acc stays in VGPRs), plain fminf (no asm
//   constraints), 8 fmin per j-tile = 1 VALU op/entry. Staging from R15
//   verbatim (linear global_load_lds, plane-separated B, dbuf, 0 conflicts).
//   Zero-lane B reads hit a 16B zeroed LDS scratch, stride 0 (broadcast).

namespace {

constexpr int kB = 16;
constexpr int kN = 4096;
constexpr int kPlane = kB * kN;
constexpr int kStage = 512;               // points per LDS stage
constexpr int kNS = kN / kStage;          // 8 stages
constexpr float kScale = 1.0f / (float)(kB * kN);

typedef short bf16x8 __attribute__((ext_vector_type(8)));
typedef float f32x4 __attribute__((ext_vector_type(4)));
typedef unsigned short u16;

__device__ inline u16 bf16_rn(float f) {
  union { float f; unsigned u; } v; v.f = f;
  unsigned r = v.u + 0x7fffu + ((v.u >> 16) & 1u);
  return (u16)(r >> 16);
}
__device__ inline float bf16_f(u16 h) {
  union { unsigned u; float f; } v; v.u = (unsigned)h << 16;
  return v.f;
}
__device__ inline unsigned pk2(u16 lo, u16 hi) {
  return (unsigned)lo | ((unsigned)hi << 16);
}

__global__ void init_out(float* out) { out[0] = 0.0f; }

// One thread per point p: A row (row-major 32B at p*32) and B row
// (plane-separated per stage: [cloud][stg][khalf][pl] 16B) for BOTH inputs.
// A u16[16]: [xh0..2, xl0..2, xh0..2, xl0..2, x2h, x2l, 1, 1]
// B u16[16]: [-2yh0..2, -2yh0..2, -2yl0..2, -2yl0..2, 1, 1, y2h, y2l]
__global__ __launch_bounds__(256) void cd_prep(
    const float* __restrict__ pred, const float* __restrict__ targ,
    u16* __restrict__ Apred, u16* __restrict__ Atarg,
    u16* __restrict__ Bpred, u16* __restrict__ Btarg,
    float* __restrict__ out) {
  const int p = blockIdx.x * 256 + threadIdx.x;   // 0..kPlane-1
  if (p == 0) out[0] = 0.0f;
  const int cloud = p >> 12, q = p & (kN - 1);
  const int stg = q >> 9, pl = q & (kStage - 1);
  // u16 offsets: B plane-sep = cloud*65536 + stg*8192 + h*4096 + pl*8
  const size_t boff = (size_t)cloud * 65536 + (size_t)stg * 8192 + (size_t)pl * 8;
  const u16 one = 0x3F80;

  const float* srcs[2] = {pred, targ};
  u16* adsts[2] = {Apred, Atarg};
  u16* bdsts[2] = {Bpred, Btarg};
#pragma unroll
  for (int which = 0; which < 2; ++which) {
    const float a = srcs[which][3 * p], c = srcs[which][3 * p + 1],
                d = srcs[which][3 * p + 2];
    const u16 ah = bf16_rn(a), ch = bf16_rn(c), dh = bf16_rn(d);
    const u16 al = bf16_rn(a - bf16_f(ah));
    const u16 cl = bf16_rn(c - bf16_f(ch));
    const u16 dl = bf16_rn(d - bf16_f(dh));
    const float s2 = fmaf(a, a, fmaf(c, c, d * d));
    const u16 s2h = bf16_rn(s2);
    const u16 s2l = bf16_rn(s2 - bf16_f(s2h));
    {  // A row
      uint4 w0, w1;
      w0.x = pk2(ah, ch); w0.y = pk2(dh, al); w0.z = pk2(cl, dl); w0.w = pk2(ah, ch);
      w1.x = pk2(dh, al); w1.y = pk2(cl, dl); w1.z = pk2(s2h, s2l); w1.w = pk2(one, one);
      uint4* dst = reinterpret_cast<uint4*>(adsts[which] + (size_t)p * 16);
      dst[0] = w0; dst[1] = w1;
    }
    {  // B row (-2 scale is exact in bf16)
      const u16 nah = bf16_rn(-2.0f * bf16_f(ah));
      const u16 nch = bf16_rn(-2.0f * bf16_f(ch));
      const u16 ndh = bf16_rn(-2.0f * bf16_f(dh));
      const u16 nal = bf16_rn(-2.0f * bf16_f(al));
      const u16 ncl = bf16_rn(-2.0f * bf16_f(cl));
      const u16 ndl = bf16_rn(-2.0f * bf16_f(dl));
      uint4 w0, w1;
      w0.x = pk2(nah, nch); w0.y = pk2(ndh, nah); w0.z = pk2(nch, ndh); w0.w = pk2(nal, ncl);
      w1.x = pk2(ndl, nal); w1.y = pk2(ncl, ndl); w1.z = pk2(one, one); w1.w = pk2(s2h, s2l);
      *reinterpret_cast<uint4*>(bdsts[which] + boff) = w0;
      *reinterpret_cast<uint4*>(bdsts[which] + boff + 4096) = w1;
    }
  }
}

// One block = 4 waves x 32 rows = 128 rows of X (cloud, chunk); scans all kN
// opposite points staged through double-buffered LDS via global_load_lds.
// 16x16x32 A/B: lane supplies row/col=lane&15, k=(lane>>4)*8+i (k-groups 2,3
// are zero). C/D [m89]: col=lane&15, row=(lane>>4)*4+reg.
// Row-min only; xor{1,2,4,8} butterfly completes min over j; block-sum ->
// atomicAdd. Plain fminf (no asm) so VALU reads MFMA results directly.
__global__ __launch_bounds__(256) void cd_mfma(
    const u16* __restrict__ Apred, const u16* __restrict__ Atarg,
    const u16* __restrict__ Bpred, const u16* __restrict__ Btarg,
    float* __restrict__ out) {
  __shared__ uint4 Blds4[2052];   // 32 KB dbuf + 16B zero scratch @32768
  __shared__ float wsum[4];

  const int t = threadIdx.x;
  const int w = t >> 6, lane = t & 63;
  const int l15 = lane & 15, kg = lane >> 4;   // k-group 0..3
  const bool act = (kg < 2);                   // lanes 32-63: zero operands
  const int g = kg & 1;                        // k-half for active lanes
  const int chunk = blockIdx.x;      // 0..31 -> 128 rows per block
  const int cloud = blockIdx.y;      // 0..15
  const int dir = blockIdx.z;        // 0: pred rows vs targ; 1: swapped
  const u16* __restrict__ A = dir ? Atarg : Apred;
  const u16* __restrict__ B = dir ? Bpred : Btarg;

  // ---- A fragments: rows band+l15 (af0) and band+16+l15 (af1) ----
  const int arow0 = cloud * kN + chunk * 128 + w * 32 + l15;
  union { uint4 u; bf16x8 v; } af0, af1;
  af0.u = make_uint4(0, 0, 0, 0);
  af1.u = make_uint4(0, 0, 0, 0);
  if (act) {
    af0.u = *reinterpret_cast<const uint4*>(A + (size_t)arow0 * 16 + g * 8);
    af1.u = *reinterpret_cast<const uint4*>(A + (size_t)(arow0 + 16) * 16 + g * 8);
  }

  // ---- staging setup: linear copy, 4 x global_load_lds(16B) per thread ----
  const char* bcloud = (const char*)B + (size_t)cloud * 131072;  // 128KB/cloud
  char* ldsbase = (char*)Blds4;
#define STAGE(st, buf)                                                        \
  {                                                                           \
    const char* _src = bcloud + (size_t)(st) * 16384;                         \
    char* _dst = ldsbase + (buf) * 16384;                                     \
    _Pragma("unroll")                                                         \
    for (int i = 0; i < 4; ++i) {                                             \
      __builtin_amdgcn_global_load_lds(                                       \
          (const __attribute__((address_space(1))) void*)(_src +              \
              ((w * 4 + i) * 64 + lane) * 16),                                \
          (__attribute__((address_space(3))) void*)(_dst + (w * 4 + i) * 1024),\
          16, 0, 0);                                                          \
    }                                                                         \
  }

  // B read addressing: active lanes walk their plane; zero lanes re-read the
  // 16B zero scratch (uniform broadcast) with stride 0.
  const int rb0 = act ? (g * 8192 + l15 * 16) : 32768;
  const int rstep = act ? 256 : 0;       // bytes per j-tile (16 pts x 16B)
  const int bufstep = act ? 16384 : 0;

  f32x4 z4;
#pragma unroll
  for (int r = 0; r < 4; ++r) z4[r] = 0.0f;
  float rmin0[4], rmin1[4];
#pragma unroll
  for (int r = 0; r < 4; ++r) { rmin0[r] = 1e30f; rmin1[r] = 1e30f; }

  STAGE(0, 0);
  if (t == 0) Blds4[2048] = make_uint4(0, 0, 0, 0);   // zero scratch
  __syncthreads();   // buf0 + scratch ready

  for (int st = 0; st < kNS; ++st) {
    if (st < kNS - 1) STAGE(st + 1, (st + 1) & 1);
    const char* pb = ldsbase + rb0 + (st & 1) * bufstep;
#pragma unroll 4
    for (int jt = 0; jt < kStage / 16; ++jt) {   // 32 j-tiles of 16 cols
      union { uint4 u; bf16x8 v; } bu;
      bu.u = *reinterpret_cast<const uint4*>(pb);
      pb += rstep;
      const f32x4 s0 =
          __builtin_amdgcn_mfma_f32_16x16x32_bf16(af0.v, bu.v, z4, 0, 0, 0);
      const f32x4 s1 =
          __builtin_amdgcn_mfma_f32_16x16x32_bf16(af1.v, bu.v, z4, 0, 0, 0);
#pragma unroll
      for (int r = 0; r < 4; ++r) {
        rmin0[r] = fminf(rmin0[r], s0[r]);
        rmin1[r] = fminf(rmin1[r], s1[r]);
      }
    }
    __syncthreads();   // next-stage loads landed; compute done before overwrite
  }
#undef STAGE

  // Complete row-mins: butterfly over the 16 lanes of each k-group
  // (same rows, different cols j).
#pragma unroll
  for (int sh = 1; sh < 16; sh <<= 1) {
#pragma unroll
    for (int r = 0; r < 4; ++r) {
      rmin0[r] = fminf(rmin0[r], __shfl_xor(rmin0[r], sh, 64));
      rmin1[r] = fminf(rmin1[r], __shfl_xor(rmin1[r], sh, 64));
    }
  }
  // Lane group kg holds rows kg*4+r (af0: band+, af1: band+16+). Lanes with
  // l15==0 (4 per wave, disjoint rows) contribute; reduce across groups.
  float s = 0.0f;
#pragma unroll
  for (int r = 0; r < 4; ++r) s += rmin0[r] + rmin1[r];
  s = (l15 == 0) ? s : 0.0f;
  s += __shfl_xor(s, 16, 64);
  s += __shfl_xor(s, 32, 64);
  if (lane == 0) wsum[w] = s;
  __syncthreads();
  if (t == 0)
    atomicAdd(out, (wsum[0] + wsum[1] + wsum[2] + wsum[3]) * kScale);
}

// ---------- fallback (small ws): R5-style pk_fma direct kernel ----------
template <int KX>
__global__ __launch_bounds__(256) void chamfer_direct(
    const float* __restrict__ pred, const float* __restrict__ targ,
    float* __restrict__ out) {
  __shared__ float4 tA[128], tB[128];
  const int t = threadIdx.x;
  const int xb = blockIdx.x, b = blockIdx.y, dir = blockIdx.z;
  const float* __restrict__ X = dir ? targ : pred;
  const float* __restrict__ Y = dir ? pred : targ;
  float2 xx2[KX], xy2[KX], xz2[KX];
  float x2[KX], mn[KX];
  const int ibase = b * kN + xb * (256 * KX) + t;
#pragma unroll
  for (int k = 0; k < KX; ++k) {
    const int i = ibase + k * 256;
    const float a = X[3 * i], c = X[3 * i + 1], d = X[3 * i + 2];
    x2[k] = fmaf(a, a, fmaf(c, c, d * d));
    xx2[k] = make_float2(-2.0f * a, -2.0f * a);
    xy2[k] = make_float2(-2.0f * c, -2.0f * c);
    xz2[k] = make_float2(-2.0f * d, -2.0f * d);
    mn[k] = 1e30f;
  }
  for (int t0 = 0; t0 < kN; t0 += 256) {
    __syncthreads();
    if (t < 128) {
      const int j0 = 3 * (b * kN + t0 + 2 * t);
      const float a0 = Y[j0], c0 = Y[j0 + 1], d0 = Y[j0 + 2];
      const float a1 = Y[j0 + 3], c1 = Y[j0 + 4], d1 = Y[j0 + 5];
      tA[t] = make_float4(a0, a1, c0, c1);
      tB[t] = make_float4(d0, d1, fmaf(a0, a0, fmaf(c0, c0, d0 * d0)),
                          fmaf(a1, a1, fmaf(c1, c1, d1 * d1)));
    }
    __syncthreads();
    for (int jj = 0; jj < 128; ++jj) {
      const float4 qa = tA[jj], qb = tB[jj];
      const float2 qx = make_float2(qa.x, qa.y), qy = make_float2(qa.z, qa.w);
      const float2 qz = make_float2(qb.x, qb.y), qw = make_float2(qb.z, qb.w);
#pragma unroll
      for (int k = 0; k < KX; ++k) {
        float2 acc;
        asm("v_pk_fma_f32 %0, %1, %2, %3\n\t"
            "v_pk_fma_f32 %0, %4, %5, %0\n\t"
            "v_pk_fma_f32 %0, %6, %7, %0"
            : "=&v"(acc)
            : "v"(xz2[k]), "v"(qz), "v"(qw), "v"(xy2[k]), "v"(qy),
              "v"(xx2[k]), "v"(qx));
        asm("v_min3_f32 %0, %0, %1, %2" : "+v"(mn[k]) : "v"(acc.x), "v"(acc.y));
      }
    }
  }
  float s = 0.0f;
#pragma unroll
  for (int k = 0; k < KX; ++k) s += x2[k] + mn[k];
  for (int o = 32; o > 0; o >>= 1) s += __shfl_down(s, o, 64);
  __shared__ float wsum[4];
  const int lane = t & 63, wv = t >> 6;
  if (lane == 0) wsum[wv] = s;
  __syncthreads();
  if (t == 0)
    atomicAdd(out, (wsum[0] + wsum[1] + wsum[2] + wsum[3]) * kScale);
}

}  // namespace

extern "C" void kernel_launch(void* const* d_in, const int* in_sizes, int n_in,
                              void* d_out, int out_size, void* d_ws,
                              size_t ws_size, hipStream_t stream) {
  const float* pred = (const float*)d_in[0];
  const float* targ = (const float*)d_in[1];
  float* out = (float*)d_out;

  const size_t needOne = (size_t)kPlane * 16 * sizeof(u16);   // 2 MB each
  if (ws_size >= 4 * needOne) {                               // 8 MB
    u16* Apred = (u16*)d_ws;
    u16* Atarg = (u16*)((char*)d_ws + needOne);
    u16* Bpred = (u16*)((char*)d_ws + 2 * needOne);
    u16* Btarg = (u16*)((char*)d_ws + 3 * needOne);
    cd_prep<<<dim3(kPlane / 256), 256, 0, stream>>>(pred, targ, Apred, Atarg,
                                                    Bpred, Btarg, out);
    cd_mfma<<<dim3(32, kB, 2), 256, 0, stream>>>(Apred, Atarg, Bpred, Btarg,
                                                 out);
  } else {
    init_out<<<dim3(1), dim3(1), 0, stream>>>(out);
    constexpr int KX = 8;
    dim3 grid(kN / (256 * KX), kB, 2);
    chamfer_direct<KX><<<grid, 256, 0, stream>>>(pred, targ, out);
  }
}